// Round 6
// baseline (12140.735 us; speedup 1.0000x reference)
//
#include <hip/hip_runtime.h>

#define BB 128
#define TT 1024
#define II 256
#define HH 512
#define OO 256
#define KK 768

typedef _Float16 half8 __attribute__((ext_vector_type(8)));
typedef _Float16 half4v __attribute__((ext_vector_type(4)));
typedef float f32x4 __attribute__((ext_vector_type(4)));
typedef unsigned long long u64_t;

__device__ __forceinline__ float sigm(float x) { return 1.f / (1.f + __expf(-x)); }
__device__ __forceinline__ float tanhfast(float x) {
  float e = __expf(-2.f * fabsf(x));
  return copysignf((1.f - e) / (1.f + e), x);
}

// ---------- one-time: x [B][T][I] fp32 -> x16 [T][B][I] fp16 (R5-proven) ----------
__global__ void __launch_bounds__(64)
prep_x(const float* __restrict__ x, _Float16* __restrict__ x16)
{
  const int bid = blockIdx.x;          // t*BB + b
  const int b = bid & (BB - 1), t = bid >> 7;
  const int tid = threadIdx.x;
  float4 v = *(const float4*)(x + ((size_t)b * TT + t) * II + tid * 4);
  half4v h;
  h[0] = (_Float16)v.x; h[1] = (_Float16)v.y; h[2] = (_Float16)v.z; h[3] = (_Float16)v.w;
  *(half4v*)(x16 + (size_t)bid * II + tid * 4) = h;
}

// ---------- persistent LSTM ----------
// grid=256 cooperative (4 batch-group domains x 64 hidden-groups), block=256.
// W fp16 fragments in REGISTERS (96 VGPR, loaded once). x from x16 (plain loads).
// h exchange: agent-scope atomic stores/loads through L3 (coherence point).
// Domain barrier: 64 padded flag words; arrival = RELEASE atomic store (no RMW
// contention); poll = wave0's 64 lanes ACQUIRE-load one slot each, __all(>=ep).
// This is cg::grid.sync's handshake, scoped to 64 WGs and without ~30us spin.
// (R2 failed: relaxed arrival -> flag visible before h-stores. R3 failed:
// plain h-loads served stale from non-invalidated XCD L2. Both fixed here.)
__global__ void __launch_bounds__(256, 1)
lstm_persist(const _Float16* __restrict__ x16,
             const float* __restrict__ Wf, const float* __restrict__ Wi,
             const float* __restrict__ Wc, const float* __restrict__ Wo,
             const float* __restrict__ bfp, const float* __restrict__ bip,
             const float* __restrict__ bcp, const float* __restrict__ bop,
             const float* __restrict__ Wlin, const float* __restrict__ blin,
             float* __restrict__ out,
             _Float16* __restrict__ hbuf,   // [2][BB][HH] fp16, atomic-only traffic
             int* __restrict__ flags)       // 256 slots x 64B, zeroed per launch
{
  extern __shared__ float pre[];  // [32*33] preact exchange / epilogue staging

  const int gid = blockIdx.x;
  const int gb = gid >> 6, gh = gid & 63;
  const int tid = threadIdx.x;
  const int wave = tid >> 6, lane = tid & 63;
  const int wm = wave >> 1, wn = wave & 1;
  const int r = lane & 15, q = lane >> 4;
  const int brow = gb * 32 + wm * 16 + r;   // A (batch) row this lane feeds
  const int c = wn * 16 + r;                // B col 0..31 = gate*8 + unit
  const int g = c >> 3, u = c & 7;

  // ---- one-time: W fragments fp32 -> fp16 registers ----
  const float* Wg = (g == 0) ? Wf : (g == 1) ? Wi : (g == 2) ? Wc : Wo;
  const float* wsrc = Wg + (size_t)(gh * 8 + u) * KK + q * 8;
  half8 wfrag[24];
#pragma unroll
  for (int ks = 0; ks < 24; ++ks) {
    float4 w0 = *(const float4*)(wsrc + ks * 32);
    float4 w1 = *(const float4*)(wsrc + ks * 32 + 4);
    half8 h;
    h[0] = (_Float16)w0.x; h[1] = (_Float16)w0.y; h[2] = (_Float16)w0.z; h[3] = (_Float16)w0.w;
    h[4] = (_Float16)w1.x; h[5] = (_Float16)w1.y; h[6] = (_Float16)w1.z; h[7] = (_Float16)w1.w;
    wfrag[ks] = h;
  }

  const int grow = tid >> 3, gu = tid & 7;
  const int gcol = gh * 8 + gu;
  const float bfv = bfp[gcol], biv = bip[gcol], bcv = bcp[gcol], bov = bop[gcol];
  float C = 0.0f;

  // ================= time loop =================
  for (int t = 0; t < TT; ++t) {
    // x_t fragments (plain loads; x16 is read-only prep output)
    const _Float16* xr = x16 + ((size_t)t * BB + brow) * II;
    half8 xa[8];
#pragma unroll
    for (int ks = 0; ks < 8; ++ks)
      xa[ks] = *(const half8*)(xr + ks * 32 + q * 8);

    f32x4 acc = {0.f, 0.f, 0.f, 0.f};

    // h_t fragments via agent atomic u64 loads (served at L3 -> always fresh)
    if (t > 0) {
      const u64_t* hp = (const u64_t*)(hbuf + (size_t)(t & 1) * BB * HH +
                                       (size_t)brow * HH) + q * 2;
      half8 ah[16];
#pragma unroll
      for (int ks = 0; ks < 16; ++ks) {
        u64_t w0 = __hip_atomic_load(hp + ks * 8, __ATOMIC_RELAXED, __HIP_MEMORY_SCOPE_AGENT);
        u64_t w1 = __hip_atomic_load(hp + ks * 8 + 1, __ATOMIC_RELAXED, __HIP_MEMORY_SCOPE_AGENT);
        half4v lo = __builtin_bit_cast(half4v, w0);
        half4v hi = __builtin_bit_cast(half4v, w1);
        half8 a;
        a[0] = lo[0]; a[1] = lo[1]; a[2] = lo[2]; a[3] = lo[3];
        a[4] = hi[0]; a[5] = hi[1]; a[6] = hi[2]; a[7] = hi[3];
        ah[ks] = a;
      }
#pragma unroll
      for (int ks = 0; ks < 8; ++ks)
        acc = __builtin_amdgcn_mfma_f32_16x16x32_f16(xa[ks], wfrag[ks], acc, 0, 0, 0);
#pragma unroll
      for (int ks = 0; ks < 16; ++ks)
        acc = __builtin_amdgcn_mfma_f32_16x16x32_f16(ah[ks], wfrag[8 + ks], acc, 0, 0, 0);
    } else {
#pragma unroll
      for (int ks = 0; ks < 8; ++ks)
        acc = __builtin_amdgcn_mfma_f32_16x16x32_f16(xa[ks], wfrag[ks], acc, 0, 0, 0);
    }

    // D layout: col = lane&15, row = (lane>>4)*4 + i
#pragma unroll
    for (int i = 0; i < 4; ++i)
      pre[(wm * 16 + q * 4 + i) * 33 + wn * 16 + r] = acc[i];
    __syncthreads();

    // gates + state update; pack 2 fp16 per agent atomic u32 store
    {
      float pf = pre[grow * 33 + gu]      + bfv;
      float pi = pre[grow * 33 + 8 + gu]  + biv;
      float pc = pre[grow * 33 + 16 + gu] + bcv;
      float po = pre[grow * 33 + 24 + gu] + bov;
      float fg = sigm(pf), ig = sigm(pi), og = sigm(po);
      float cg = tanhfast(pc);
      C = fg * C + ig * cg;
      float hn = og * tanhfast(C);
      unsigned hv;
      { _Float16 h16 = (_Float16)hn; hv = (unsigned)__builtin_bit_cast(unsigned short, h16); }
      unsigned other = (unsigned)__shfl_down((int)hv, 1);
      if ((gu & 1) == 0) {
        unsigned val = hv | (other << 16);
        unsigned idx = (unsigned)(((gb * 32 + grow) * HH + gh * 8 + gu) >> 1);
        __hip_atomic_store((unsigned*)hbuf + (size_t)((t + 1) & 1) * (BB * HH / 2) + idx,
                           val, __ATOMIC_RELAXED, __HIP_MEMORY_SCOPE_AGENT);
      }
    }
    __syncthreads();  // every wave's h-stores vmcnt-drained before arrival

    // ---- domain barrier, epoch t+1 ----
    if (tid == 0)
      __hip_atomic_store(flags + (size_t)gid * 16, t + 1,
                         __ATOMIC_RELEASE, __HIP_MEMORY_SCOPE_AGENT);
    if (wave == 0) {
      const int* fp = flags + (size_t)(gb * 64 + lane) * 16;
      for (;;) {
        int v = __hip_atomic_load(fp, __ATOMIC_ACQUIRE, __HIP_MEMORY_SCOPE_AGENT);
        if (__all(v >= t + 1)) break;
        __builtin_amdgcn_s_sleep(1);
      }
    }
    __syncthreads();
  }

  // ===== epilogue (in-domain rows): out = h_T @ W_lin^T + b_lin =====
  {
    const int l = gid & 63;
    const int b = gb * 32 + (l >> 1);   // this domain's rows only
    const int o0 = (l & 1) * 128;
    if (tid < 128) {
      // h_T lives in buffer 0 (last write at t=1023 -> buffer (t+1)&1 = 0)
      u64_t v = __hip_atomic_load((const u64_t*)hbuf + ((size_t)b * HH) / 4 + tid,
                                  __ATOMIC_RELAXED, __HIP_MEMORY_SCOPE_AGENT);
      half4v h4 = __builtin_bit_cast(half4v, v);
      pre[4 * tid]     = (float)h4[0];
      pre[4 * tid + 1] = (float)h4[1];
      pre[4 * tid + 2] = (float)h4[2];
      pre[4 * tid + 3] = (float)h4[3];
    }
    __syncthreads();
    if (tid < 128) {
      int o = o0 + tid;
      float a2 = blin[o];
      const float4* wr = (const float4*)(Wlin + (size_t)o * HH);
#pragma unroll 4
      for (int j = 0; j < 128; ++j) {
        float4 wv = wr[j];
        a2 += wv.x * pre[4 * j] + wv.y * pre[4 * j + 1] +
              wv.z * pre[4 * j + 2] + wv.w * pre[4 * j + 3];
      }
      out[(size_t)b * OO + o] = a2;
    }
  }
}

extern "C" void kernel_launch(void* const* d_in, const int* in_sizes, int n_in,
                              void* d_out, int out_size, void* d_ws, size_t ws_size,
                              hipStream_t stream) {
  const float* x    = (const float*)d_in[0];
  const float* Wf   = (const float*)d_in[1];
  const float* bf_  = (const float*)d_in[2];
  const float* Wi   = (const float*)d_in[3];
  const float* bi_  = (const float*)d_in[4];
  const float* Wc   = (const float*)d_in[5];
  const float* bc_  = (const float*)d_in[6];
  const float* Wo   = (const float*)d_in[7];
  const float* bo_  = (const float*)d_in[8];
  const float* Wlin = (const float*)d_in[9];
  const float* blin = (const float*)d_in[10];
  float* out = (float*)d_out;

  // ws: flags [0,16K) | hbuf [16K,16K+256K) | x16 [4M,4M+64M)  (needs 71,303,168 B,
  // same total as R5's proven path-A layout)
  int*      flags = (int*)d_ws;
  _Float16* hbuf  = (_Float16*)((char*)d_ws + 16384);
  _Float16* x16   = (_Float16*)((char*)d_ws + 4194304);

  hipMemsetAsync(d_ws, 0, 16384, stream);  // zero barrier flags every launch
  prep_x<<<dim3(TT * BB), dim3(64), 0, stream>>>(x, x16);

  const unsigned smem = 32 * 33 * 4;  // 4224 B
  hipFuncSetAttribute((const void*)lstm_persist,
                      hipFuncAttributeMaxDynamicSharedMemorySize, (int)smem);
  void* args[] = {(void*)&x16, (void*)&Wf, (void*)&Wi, (void*)&Wc, (void*)&Wo,
                  (void*)&bf_, (void*)&bi_, (void*)&bc_, (void*)&bo_,
                  (void*)&Wlin, (void*)&blin, (void*)&out, (void*)&hbuf, (void*)&flags};
  hipLaunchCooperativeKernel((const void*)lstm_persist, dim3(256), dim3(256),
                             args, smem, stream);
}

// Round 7
// 8478.332 us; speedup vs baseline: 1.4320x; 1.4320x over previous
//
#include <hip/hip_runtime.h>

#define BB 128
#define TT 1024
#define II 256
#define HH 512
#define OO 256
#define KK 768

typedef _Float16 half8 __attribute__((ext_vector_type(8)));
typedef _Float16 half4v __attribute__((ext_vector_type(4)));
typedef float f32x4 __attribute__((ext_vector_type(4)));
typedef unsigned long long u64_t;

__device__ __forceinline__ float sigm(float x) { return 1.f / (1.f + __expf(-x)); }
__device__ __forceinline__ float tanhfast(float x) {
  float e = __expf(-2.f * fabsf(x));
  return copysignf((1.f - e) / (1.f + e), x);
}

// ---------- one-time: x [B][T][I] fp32 -> x16 [T][B][I] fp16 (R5-proven) ----------
__global__ void __launch_bounds__(64)
prep_x(const float* __restrict__ x, _Float16* __restrict__ x16)
{
  const int bid = blockIdx.x;          // t*BB + b
  const int b = bid & (BB - 1), t = bid >> 7;
  const int tid = threadIdx.x;
  float4 v = *(const float4*)(x + ((size_t)b * TT + t) * II + tid * 4);
  half4v h;
  h[0] = (_Float16)v.x; h[1] = (_Float16)v.y; h[2] = (_Float16)v.z; h[3] = (_Float16)v.w;
  *(half4v*)(x16 + (size_t)bid * II + tid * 4) = h;
}

// ---------- persistent LSTM ----------
// grid=256 cooperative: 8 batch-group domains (16 rows) x 32 hidden-groups
// (16 units = 64 gate-cols; wave wn = gate wn). block=256 (4 waves).
// W fp16 fragments in registers (96 VGPR). h exchange: relaxed agent atomics
// (L3-coherent, R6-proven); domain h slab staged ONCE per WG into swizzled LDS
// (4x traffic cut vs R6). Barrier: release arrival flag + RELAXED poll +
// single acquire fence at exit (R6's per-poll ACQUIRE caused an L2
// invalidation storm: FETCH 906 MB).
__global__ void __launch_bounds__(256, 1)
lstm_persist(const _Float16* __restrict__ x16,
             const float* __restrict__ Wf, const float* __restrict__ Wi,
             const float* __restrict__ Wc, const float* __restrict__ Wo,
             const float* __restrict__ bfp, const float* __restrict__ bip,
             const float* __restrict__ bcp, const float* __restrict__ bop,
             const float* __restrict__ Wlin, const float* __restrict__ blin,
             float* __restrict__ out,
             _Float16* __restrict__ hbuf,   // [2][BB][HH] fp16, atomic-only traffic
             int* __restrict__ flags)       // 256 slots x 64B, zeroed per launch
{
  __shared__ __align__(16) char hsb[16 * 1024];  // h_t staging [16 rows][512] fp16, swizzled
  __shared__ float pre[16 * 68];                 // [16 rows][64+pad] preacts

  const int gid = blockIdx.x;
  const int gb = gid >> 5, gh = gid & 31;
  const int tid = threadIdx.x;
  const int wn = tid >> 6, lane = tid & 63;      // wave index == gate index
  const int r = lane & 15, q = lane >> 4;

  // ---- one-time: W fragments fp32 -> fp16 registers ----
  // lane (r,q) of wave wn: B col = unit r of gate wn; holds k = ks*32 + q*8 ..+8
  const float* Wg = (wn == 0) ? Wf : (wn == 1) ? Wi : (wn == 2) ? Wc : Wo;
  const float* wsrc = Wg + (size_t)(gh * 16 + r) * KK + q * 8;
  half8 wfrag[24];
#pragma unroll
  for (int ks = 0; ks < 24; ++ks) {
    float4 w0 = *(const float4*)(wsrc + ks * 32);
    float4 w1 = *(const float4*)(wsrc + ks * 32 + 4);
    half8 h;
    h[0] = (_Float16)w0.x; h[1] = (_Float16)w0.y; h[2] = (_Float16)w0.z; h[3] = (_Float16)w0.w;
    h[4] = (_Float16)w1.x; h[5] = (_Float16)w1.y; h[6] = (_Float16)w1.z; h[7] = (_Float16)w1.w;
    wfrag[ks] = h;
  }

  // gate-update mapping: thread owns (row = tid>>4, unit = tid&15)
  const int grow = tid >> 4, gu = tid & 15;
  const int gcol = gh * 16 + gu;
  const float bfv = bfp[gcol], biv = bip[gcol], bcv = bcp[gcol], bov = bop[gcol];
  float C = 0.0f;

  const int arow = gb * 16 + r;                  // A batch row this lane feeds
  const int swz = (r & 7) << 4;                  // fragment-read swizzle

  // ================= time loop =================
  for (int t = 0; t < TT; ++t) {
    // x_t fragments (plain loads, issued before the barrier wait)
    const _Float16* xr = x16 + ((size_t)t * BB + arow) * II;
    half8 xa[8];
#pragma unroll
    for (int ks = 0; ks < 8; ++ks)
      xa[ks] = *(const half8*)(xr + ks * 32 + q * 8);

    if (t > 0) {
      // ---- wait for epoch t (h_t published domain-wide) ----
      if (wn == 0) {
        const int* fp = flags + (size_t)(gb * 32 + (lane & 31)) * 16;
        for (;;) {
          int v = __hip_atomic_load(fp, __ATOMIC_RELAXED, __HIP_MEMORY_SCOPE_AGENT);
          if (__all(v >= t)) break;
          __builtin_amdgcn_s_sleep(1);
        }
        __builtin_amdgcn_fence(__ATOMIC_ACQUIRE, "agent");  // once per step
      }
      __syncthreads();

      // ---- stage h_t (16 rows x 512) into swizzled LDS; atomic u64 loads ----
      {
        const int srow = tid >> 4, schunk = tid & 15;   // row, 32-half chunk
        const u64_t* hp = (const u64_t*)(hbuf + (size_t)(t & 1) * BB * HH +
                                         (size_t)(gb * 16 + srow) * HH + schunk * 32);
        char* dst = hsb + srow * 1024;
        const int cb = schunk * 64, sw = (srow & 7) << 4;
#pragma unroll
        for (int j = 0; j < 8; ++j) {
          u64_t v = __hip_atomic_load(hp + j, __ATOMIC_RELAXED, __HIP_MEMORY_SCOPE_AGENT);
          *(u64_t*)(dst + ((cb + j * 8) ^ sw)) = v;
        }
      }
      __syncthreads();
    }

    // ---- MFMA: pre[16 x 64] = A[16 x 768] * W^T (wave wn -> gate wn) ----
    f32x4 acc = {0.f, 0.f, 0.f, 0.f};
#pragma unroll
    for (int ks = 0; ks < 8; ++ks)
      acc = __builtin_amdgcn_mfma_f32_16x16x32_f16(xa[ks], wfrag[ks], acc, 0, 0, 0);
    if (t > 0) {
      const char* hrow = hsb + r * 1024;
#pragma unroll
      for (int ks = 0; ks < 16; ++ks) {
        half8 a = *(const half8*)(hrow + ((ks * 64 + q * 16) ^ swz));
        acc = __builtin_amdgcn_mfma_f32_16x16x32_f16(a, wfrag[8 + ks], acc, 0, 0, 0);
      }
    }
    // D layout: col = lane&15 (unit), row = q*4 + i
#pragma unroll
    for (int i = 0; i < 4; ++i)
      pre[(q * 4 + i) * 68 + wn * 16 + r] = acc[i];
    __syncthreads();

    // ---- gates + state update; pack 2 fp16 per relaxed agent u32 store ----
    {
      float pf = pre[grow * 68 + gu]      + bfv;
      float pi = pre[grow * 68 + 16 + gu] + biv;
      float pc = pre[grow * 68 + 32 + gu] + bcv;
      float po = pre[grow * 68 + 48 + gu] + bov;
      float fg = sigm(pf), ig = sigm(pi), og = sigm(po);
      float cg = tanhfast(pc);
      C = fg * C + ig * cg;
      float hn = og * tanhfast(C);
      unsigned hv;
      { _Float16 h16 = (_Float16)hn; hv = (unsigned)__builtin_bit_cast(unsigned short, h16); }
      unsigned other = (unsigned)__shfl_down((int)hv, 1);
      if (!(gu & 1)) {
        size_t ei = (size_t)((t + 1) & 1) * BB * HH +
                    (size_t)(gb * 16 + grow) * HH + gh * 16 + gu;
        __hip_atomic_store((unsigned*)hbuf + ei / 2, hv | (other << 16),
                           __ATOMIC_RELAXED, __HIP_MEMORY_SCOPE_AGENT);
      }
    }
    __syncthreads();  // compiler drains vmcnt before barrier -> h-stores complete
    if (tid == 0)
      __hip_atomic_store(flags + (size_t)gid * 16, t + 1,
                         __ATOMIC_RELEASE, __HIP_MEMORY_SCOPE_AGENT);
  }

  // ---- final domain barrier: epoch TT (h_T fully published) ----
  if (wn == 0) {
    const int* fp = flags + (size_t)(gb * 32 + (lane & 31)) * 16;
    for (;;) {
      int v = __hip_atomic_load(fp, __ATOMIC_RELAXED, __HIP_MEMORY_SCOPE_AGENT);
      if (__all(v >= TT)) break;
      __builtin_amdgcn_s_sleep(1);
    }
    __builtin_amdgcn_fence(__ATOMIC_ACQUIRE, "agent");
  }
  __syncthreads();

  // ===== epilogue (in-domain rows): out = h_T @ W_lin^T + b_lin =====
  {
    const int row = gb * 16 + (gh >> 1);   // this domain's rows only
    const int o0 = (gh & 1) * 128;
    // h_T is buffer 0 (last store at t=1023 -> buffer (t+1)&1 = 0)
    unsigned v = __hip_atomic_load((const unsigned*)hbuf + (size_t)row * (HH / 2) + tid,
                                   __ATOMIC_RELAXED, __HIP_MEMORY_SCOPE_AGENT);
    float* hf = (float*)hsb;
    hf[2 * tid]     = (float)__builtin_bit_cast(_Float16, (unsigned short)(v & 0xffffu));
    hf[2 * tid + 1] = (float)__builtin_bit_cast(_Float16, (unsigned short)(v >> 16));
    __syncthreads();
    if (tid < 128) {
      int o = o0 + tid;
      float a2 = blin[o];
      const float4* wr = (const float4*)(Wlin + (size_t)o * HH);
#pragma unroll 4
      for (int j = 0; j < 128; ++j) {
        float4 wv = wr[j];
        a2 += wv.x * hf[4 * j] + wv.y * hf[4 * j + 1] +
              wv.z * hf[4 * j + 2] + wv.w * hf[4 * j + 3];
      }
      out[(size_t)row * OO + o] = a2;
    }
  }
}

extern "C" void kernel_launch(void* const* d_in, const int* in_sizes, int n_in,
                              void* d_out, int out_size, void* d_ws, size_t ws_size,
                              hipStream_t stream) {
  const float* x    = (const float*)d_in[0];
  const float* Wf   = (const float*)d_in[1];
  const float* bf_  = (const float*)d_in[2];
  const float* Wi   = (const float*)d_in[3];
  const float* bi_  = (const float*)d_in[4];
  const float* Wc   = (const float*)d_in[5];
  const float* bc_  = (const float*)d_in[6];
  const float* Wo   = (const float*)d_in[7];
  const float* bo_  = (const float*)d_in[8];
  const float* Wlin = (const float*)d_in[9];
  const float* blin = (const float*)d_in[10];
  float* out = (float*)d_out;

  // ws: flags [0,16K) | hbuf [16K,16K+256K) | x16 [4M,4M+64M)  (needs 71,303,168 B;
  // R6 ran with this layout -> ws_size is sufficient)
  int*      flags = (int*)d_ws;
  _Float16* hbuf  = (_Float16*)((char*)d_ws + 16384);
  _Float16* x16   = (_Float16*)((char*)d_ws + 4194304);

  hipMemsetAsync(d_ws, 0, 16384, stream);  // zero barrier flags every launch
  prep_x<<<dim3(TT * BB), dim3(64), 0, stream>>>(x, x16);

  void* args[] = {(void*)&x16, (void*)&Wf, (void*)&Wi, (void*)&Wc, (void*)&Wo,
                  (void*)&bf_, (void*)&bi_, (void*)&bc_, (void*)&bo_,
                  (void*)&Wlin, (void*)&blin, (void*)&out, (void*)&hbuf, (void*)&flags};
  hipLaunchCooperativeKernel((const void*)lstm_persist, dim3(256), dim3(256),
                             args, 0, stream);
}

// Round 9
// 6460.009 us; speedup vs baseline: 1.8794x; 1.3124x over previous
//
#include <hip/hip_runtime.h>

#define BB 128
#define TT 1024
#define II 256
#define HH 512
#define OO 256
#define KK 768

typedef _Float16 half8 __attribute__((ext_vector_type(8)));
typedef _Float16 half4v __attribute__((ext_vector_type(4)));
typedef float f32x4 __attribute__((ext_vector_type(4)));

__device__ __forceinline__ float sigm(float x) { return 1.f / (1.f + __expf(-x)); }
__device__ __forceinline__ float tanhfast(float x) {
  float e = __expf(-2.f * fabsf(x));
  return copysignf((1.f - e) / (1.f + e), x);
}

// ---------- one-time: W -> fp16 fragment-linear, QUAD-INTERLEAVED columns ----------
// B-tile col c (0..15) = local_unit(c>>2)*4 + gate(c&3); unit = gh*8 + wn*4 + (c>>2).
// W16[(((gh*2+wn)*24 + ks)*64 + lane)*8], lane = q*16 + r holds B[col r][ks*32+q*8 ..+8].
__global__ void __launch_bounds__(64)
prep_w(const float* __restrict__ Wf, const float* __restrict__ Wi,
       const float* __restrict__ Wc, const float* __restrict__ Wo,
       _Float16* __restrict__ W16)
{
  const int bid = blockIdx.x;          // (gh*2+wn)*24 + ks
  const int ks = bid % 24;
  const int gw = bid / 24;
  const int wn = gw & 1, gh = gw >> 1;
  const int lane = threadIdx.x;
  const int r = lane & 15, q = lane >> 4;
  const int lu = r >> 2, g = r & 3;
  const int unit = gh * 8 + wn * 4 + lu;
  const float* Wg = (g == 0) ? Wf : (g == 1) ? Wi : (g == 2) ? Wc : Wo;
  const float* src = Wg + (size_t)unit * KK + ks * 32 + q * 8;
  float4 w0 = *(const float4*)src;
  float4 w1 = *(const float4*)(src + 4);
  half8 h;
  h[0] = (_Float16)w0.x; h[1] = (_Float16)w0.y; h[2] = (_Float16)w0.z; h[3] = (_Float16)w0.w;
  h[4] = (_Float16)w1.x; h[5] = (_Float16)w1.y; h[6] = (_Float16)w1.z; h[7] = (_Float16)w1.w;
  *(half8*)(W16 + ((size_t)bid * 64 + lane) * 8) = h;
}

// ---------- one-time: x [B][T][I] fp32 -> x16 [T][B][I] fp16 ----------
__global__ void __launch_bounds__(256)
prep_x(const float* __restrict__ x, _Float16* __restrict__ x16)
{
  const int t = blockIdx.x;
  for (int i = threadIdx.x; i < BB * II / 4; i += 256) {
    const int b = i >> 6, c4 = (i & 63) * 4;
    float4 v = *(const float4*)(x + ((size_t)b * TT + t) * II + c4);
    half4v h;
    h[0] = (_Float16)v.x; h[1] = (_Float16)v.y; h[2] = (_Float16)v.z; h[3] = (_Float16)v.w;
    *(half4v*)(x16 + ((size_t)t * BB + b) * II + c4) = h;
  }
}

// ---------- per-step kernel: LDS-free, barrier-free ----------
// Grid 256 (4 batch-groups x 64 hidden-groups of 8 units), block 256 (4 waves:
// wm = row half, wn = unit quad). 24 x {16B A-load, 16B B-load, MFMA}, then a
// 4x4 quad shfl-transpose gathers the 4 gates of one (row,unit) into one lane:
// gates -> C -> h with zero LDS and zero __syncthreads. Cross-step visibility
// via kernel launch boundaries (bedrock semantics, R4/R5-proven).
__global__ void __launch_bounds__(256)
lstm_step(const _Float16* __restrict__ W16, const _Float16* __restrict__ x16,
          const float* __restrict__ bfp, const float* __restrict__ bip,
          const float* __restrict__ bcp, const float* __restrict__ bop,
          _Float16* __restrict__ hbuf,  // [2][BB][HH] fp16
          float* __restrict__ Cws,      // [BB][HH] fp32
          int t)
{
  const int gid = blockIdx.x;
  const int gb = gid >> 6, gh = gid & 63;
  const int tid = threadIdx.x;
  const int wave = tid >> 6, lane = tid & 63;
  const int wm = wave >> 1, wn = wave & 1;
  const int r = lane & 15, q = lane >> 4;
  const int brow = gb * 32 + wm * 16 + r;     // A (batch) row this lane feeds

  const half8* wp = (const half8*)W16 + ((size_t)(gh * 2 + wn) * 24) * 64 + lane;
  const _Float16* xr = x16 + ((size_t)t * BB + brow) * II;
  const _Float16* hb = hbuf + (size_t)(t & 1) * BB * HH + (size_t)brow * HH;

  f32x4 acc = {0.f, 0.f, 0.f, 0.f};
#pragma unroll
  for (int ks = 0; ks < 8; ++ks) {
    half8 a = *(const half8*)(xr + ks * 32 + q * 8);
    acc = __builtin_amdgcn_mfma_f32_16x16x32_f16(a, wp[ks * 64], acc, 0, 0, 0);
  }
  if (t > 0) {
#pragma unroll
    for (int ks = 0; ks < 16; ++ks) {
      half8 a = *(const half8*)(hb + ks * 32 + q * 8);
      acc = __builtin_amdgcn_mfma_f32_16x16x32_f16(a, wp[(8 + ks) * 64], acc, 0, 0, 0);
    }
  }

  // acc[i] = pre(row wm*16+q*4+i, col wn*16+r), col = unit-quad: gate g = r&3.
  // 4x4 transpose over (g, i) within each lane quad:
  //   out[i] = ((i&m)==(g&m)) ? cur[i] : recv_partner(cur[i^m]),  m = 1 then 2.
  const int g = r & 3;
  float t1[4], s[4], pg[4];
#pragma unroll
  for (int i = 0; i < 4; ++i) s[i] = __shfl_xor(acc[i], 1);
#pragma unroll
  for (int i = 0; i < 4; ++i) t1[i] = ((i & 1) == (g & 1)) ? acc[i] : s[i ^ 1];
#pragma unroll
  for (int i = 0; i < 4; ++i) s[i] = __shfl_xor(t1[i], 2);
#pragma unroll
  for (int i = 0; i < 4; ++i) pg[i] = ((i & 2) == (g & 2)) ? t1[i] : s[i ^ 2];
  // pg[j] = preact of gate j (f,i,c,o) for (row, unit) below:
  const int row  = gb * 32 + wm * 16 + q * 4 + g;
  const int unit = gh * 8 + wn * 4 + (r >> 2);

  float pf = pg[0] + bfp[unit];
  float pi = pg[1] + bip[unit];
  float pc = pg[2] + bcp[unit];
  float po = pg[3] + bop[unit];
  const size_t gi = (size_t)row * HH + unit;
  float Cold = (t > 0) ? Cws[gi] : 0.f;
  float C = sigm(pf) * Cold + sigm(pi) * tanhfast(pc);
  Cws[gi] = C;
  hbuf[(size_t)((t + 1) & 1) * BB * HH + gi] = (_Float16)(sigm(po) * tanhfast(C));
}

// ---------- epilogue: out = h_T @ W_lin^T + b_lin ----------
__global__ void __launch_bounds__(256)
lstm_out(const _Float16* __restrict__ hbuf,  // buffer 0 holds h_T (TT even)
         const float* __restrict__ Wlin, const float* __restrict__ blin,
         float* __restrict__ out)
{
  __shared__ float hs[HH];
  const int b = blockIdx.x >> 1;
  const int o0 = (blockIdx.x & 1) * 128;
  const int tid = threadIdx.x;
  hs[2 * tid]     = (float)hbuf[(size_t)b * HH + 2 * tid];
  hs[2 * tid + 1] = (float)hbuf[(size_t)b * HH + 2 * tid + 1];
  __syncthreads();
  if (tid < 128) {
    int o = o0 + tid;
    float a2 = blin[o];
    const float4* wr = (const float4*)(Wlin + (size_t)o * HH);
#pragma unroll 4
    for (int j = 0; j < 128; ++j) {
      float4 wv = wr[j];
      a2 += wv.x * hs[4 * j] + wv.y * hs[4 * j + 1] +
            wv.z * hs[4 * j + 2] + wv.w * hs[4 * j + 3];
    }
    out[(size_t)b * OO + o] = a2;
  }
}

extern "C" void kernel_launch(void* const* d_in, const int* in_sizes, int n_in,
                              void* d_out, int out_size, void* d_ws, size_t ws_size,
                              hipStream_t stream) {
  const float* x    = (const float*)d_in[0];
  const float* Wf   = (const float*)d_in[1];
  const float* bf_  = (const float*)d_in[2];
  const float* Wi   = (const float*)d_in[3];
  const float* bi_  = (const float*)d_in[4];
  const float* Wc   = (const float*)d_in[5];
  const float* bc_  = (const float*)d_in[6];
  const float* Wo   = (const float*)d_in[7];
  const float* bo_  = (const float*)d_in[8];
  const float* Wlin = (const float*)d_in[9];
  const float* blin = (const float*)d_in[10];
  float* out = (float*)d_out;

  // ws layout (R5-proven): W16 [0,3145728) | hbuf [3145728,3407872) |
  //                        Cws [3407872,3932160) | x16 [4194304, 71303168)
  _Float16* W16  = (_Float16*)d_ws;
  _Float16* hbuf = (_Float16*)((char*)d_ws + 3145728);
  float*    Cws  = (float*)((char*)d_ws + 3407872);
  _Float16* x16  = (_Float16*)((char*)d_ws + 4194304);

  prep_w<<<dim3(64 * 2 * 24), dim3(64), 0, stream>>>(Wf, Wi, Wc, Wo, W16);
  prep_x<<<dim3(TT), dim3(256), 0, stream>>>(x, x16);
  for (int t = 0; t < TT; ++t)
    lstm_step<<<dim3(256), dim3(256), 0, stream>>>(W16, x16, bf_, bi_, bc_, bo_,
                                                   hbuf, Cws, t);
  lstm_out<<<dim3(256), dim3(256), 0, stream>>>(hbuf, Wlin, blin, out);
}